// Round 7
// baseline (2907.427 us; speedup 1.0000x reference)
//
#include <hip/hip_runtime.h>
#include <hip/hip_bf16.h>
#include <hip/hip_fp16.h>
#include <math.h>

#define B_DIM 8
#define C_DIM 256
#define N_DIM 2048
#define CQ 64
#define BG 4  // batch-group size for E reuse (ws footprint)

#define TM 64
#define TN 64
#define TK 16

typedef __attribute__((ext_vector_type(8))) short short8;   // 8 bf16 (4 VGPRs)
typedef __attribute__((ext_vector_type(4))) float floatx4;

// 3-way bf16 split: v = h + m + l + delta, |delta| <= 2^-24 |v|  (round-5 verified)
__device__ inline void split_bf16x3(float v, short& h, short& m, short& l) {
  unsigned u = __float_as_uint(v);
  unsigned short hh = (unsigned short)((u + 0x7FFFu + ((u >> 16) & 1u)) >> 16);
  float fh = __uint_as_float(((unsigned)hh) << 16);
  float r1 = v - fh;  // exact
  unsigned u1 = __float_as_uint(r1);
  unsigned short mm = (unsigned short)((u1 + 0x7FFFu + ((u1 >> 16) & 1u)) >> 16);
  float fm = __uint_as_float(((unsigned)mm) << 16);
  float r2 = r1 - fm;  // exact
  unsigned u2 = __float_as_uint(r2);
  unsigned short ll = (unsigned short)((u2 + 0x7FFFu + ((u2 >> 16) & 1u)) >> 16);
  h = (short)hh;
  m = (short)mm;
  l = (short)ll;
}

// bf16x3 product accumulate over both 32-K chunks, smallest terms first (round-5 verified)
#define BF3_ACC(z, Ah0, Ah1, Am0, Am1, Al0, Al1, Bh0, Bh1, Bm0, Bm1, Bl0, Bl1)  \
  do {                                                                          \
    z = __builtin_amdgcn_mfma_f32_16x16x32_bf16(Al0, Bh0, z, 0, 0, 0);          \
    z = __builtin_amdgcn_mfma_f32_16x16x32_bf16(Al1, Bh1, z, 0, 0, 0);          \
    z = __builtin_amdgcn_mfma_f32_16x16x32_bf16(Ah0, Bl0, z, 0, 0, 0);          \
    z = __builtin_amdgcn_mfma_f32_16x16x32_bf16(Ah1, Bl1, z, 0, 0, 0);          \
    z = __builtin_amdgcn_mfma_f32_16x16x32_bf16(Am0, Bm0, z, 0, 0, 0);          \
    z = __builtin_amdgcn_mfma_f32_16x16x32_bf16(Am1, Bm1, z, 0, 0, 0);          \
    z = __builtin_amdgcn_mfma_f32_16x16x32_bf16(Am0, Bh0, z, 0, 0, 0);          \
    z = __builtin_amdgcn_mfma_f32_16x16x32_bf16(Am1, Bh1, z, 0, 0, 0);          \
    z = __builtin_amdgcn_mfma_f32_16x16x32_bf16(Ah0, Bm0, z, 0, 0, 0);          \
    z = __builtin_amdgcn_mfma_f32_16x16x32_bf16(Ah1, Bm1, z, 0, 0, 0);          \
    z = __builtin_amdgcn_mfma_f32_16x16x32_bf16(Ah0, Bh0, z, 0, 0, 0);          \
    z = __builtin_amdgcn_mfma_f32_16x16x32_bf16(Ah1, Bh1, z, 0, 0, 0);          \
  } while (0)

// pos[b,c,n] = sum_i w[c,i]*xyz[b,n,i]
__global__ void pos_kernel(const float* __restrict__ w, const float* __restrict__ xyz,
                           float* __restrict__ pos) {
  int n = blockIdx.x * blockDim.x + threadIdx.x;
  int c = blockIdx.y;
  int b = blockIdx.z;
  const float* xp = xyz + ((long long)b * N_DIM + n) * 3;
  pos[((long long)b * C_DIM + c) * N_DIM + n] =
      w[c * 3 + 0] * xp[0] + w[c * 3 + 1] * xp[1] + w[c * 3 + 2] * xp[2];
}

// Y[b,m,n] = epi( sum_k W[m,k] * (X[b,k,n] + Xadd[b,k,n]) )  -- f32 core, round-1 verified
// mode 0: f32 out (+bias/bn/relu/res).
// mode 1: bf16x3 planes [b][m][N] (+bias)  (val)
// mode 2: bf16x3 planes transposed [b][n][M] (q; M=64)
__global__ void gemm_wx(const float* __restrict__ W,
                        const float* __restrict__ X, long long sxB,
                        const float* __restrict__ Xadd, long long saB,
                        const float* __restrict__ bias,
                        const float* __restrict__ bng, const float* __restrict__ bnb,
                        const float* __restrict__ bnm, const float* __restrict__ bnv,
                        const float* __restrict__ Res, long long srB,
                        float* __restrict__ Y, long long syB,
                        short* __restrict__ Yh, short* __restrict__ Ym,
                        short* __restrict__ Yl, int mode,
                        int M, int K) {
  const int N = N_DIM;
  int b = blockIdx.z;
  int m0 = blockIdx.y * TM;
  int n0 = blockIdx.x * TN;
  int t = threadIdx.x;
  int tx = t & 15, ty = t >> 4;
  __shared__ float As[TK][TM + 1];
  __shared__ float Bs[TK][TN];
  float acc[4][4] = {};
  const float* Xb = X + (long long)b * sxB;
  const float* Ab = Xadd ? Xadd + (long long)b * saB : nullptr;
  for (int k0 = 0; k0 < K; k0 += TK) {
#pragma unroll
    for (int v = 0; v < 4; v++) {
      int l = t * 4 + v;
      int i = l >> 4, k = l & 15;
      As[k][i] = W[(long long)(m0 + i) * K + k0 + k];
    }
#pragma unroll
    for (int v = 0; v < 4; v++) {
      int l = t * 4 + v;
      int k = l >> 6, j = l & 63;
      float x = Xb[(long long)(k0 + k) * N + n0 + j];
      if (Ab) x += Ab[(long long)(k0 + k) * N + n0 + j];
      Bs[k][j] = x;
    }
    __syncthreads();
#pragma unroll
    for (int k = 0; k < TK; k++) {
      float a[4], bb[4];
#pragma unroll
      for (int ii = 0; ii < 4; ii++) a[ii] = As[k][ty * 4 + ii];
#pragma unroll
      for (int jj = 0; jj < 4; jj++) bb[jj] = Bs[k][tx * 4 + jj];
#pragma unroll
      for (int ii = 0; ii < 4; ii++)
#pragma unroll
        for (int jj = 0; jj < 4; jj++)
          acc[ii][jj] = fmaf(a[ii], bb[jj], acc[ii][jj]);
    }
    __syncthreads();
  }
#pragma unroll
  for (int ii = 0; ii < 4; ii++) {
    int m = m0 + ty * 4 + ii;
    float sh = bias ? bias[m] : 0.f;
    bool dobn = (bng != nullptr);
    float bnsc = 0.f, bnsh = 0.f;
    if (dobn) {
      bnsc = bng[m] * rsqrtf(bnv[m] + 1e-5f);
      bnsh = bnb[m] - bnm[m] * bnsc;
    }
#pragma unroll
    for (int jj = 0; jj < 4; jj++) {
      int n = n0 + tx * 4 + jj;
      float v = acc[ii][jj] + sh;
      if (dobn) v = fmaxf(v * bnsc + bnsh, 0.f);
      if (Res) v += Res[(long long)b * srB + (long long)m * N + n];
      if (mode == 0) {
        Y[(long long)b * syB + (long long)m * N + n] = v;
      } else {
        long long idx = (mode == 1) ? ((long long)b * M + m) * N + n
                                    : ((long long)b * N + n) * M + m;
        short h, md, l;
        split_bf16x3(v, h, md, l);
        Yh[idx] = h;
        Ym[idx] = md;
        Yl[idx] = l;
      }
    }
  }
}

// E[bl,n,m] = sum_d q[b,n,d]*q[b,m,d] from pre-split qT planes [B][N][64]; no LDS.
// b = b0 + blockIdx.z (local E index = blockIdx.z).
// grid (N/64 m0, N/64 nblk, BG), block 256 = 4 waves (wave w -> n-rows nblk*64+w*16)
__global__ __launch_bounds__(256) void energy_mfma(
    const short* __restrict__ qh, const short* __restrict__ qm,
    const short* __restrict__ ql, float* __restrict__ E, int b0) {
  const int N = N_DIM;
  int bl = blockIdx.z;
  int b = b0 + bl;
  int m0 = blockIdx.x * 64;
  int n0 = blockIdx.y * 64;
  int t = threadIdx.x;
  int w = t >> 6, lane = t & 63, quad = lane >> 4, lm = lane & 15;
  long long qbase = (long long)b * N * CQ;
  long long arow = qbase + (long long)(n0 + w * 16 + lm) * CQ;
  short8 ah0 = *(const short8*)(qh + arow + quad * 8);
  short8 ah1 = *(const short8*)(qh + arow + 32 + quad * 8);
  short8 am0 = *(const short8*)(qm + arow + quad * 8);
  short8 am1 = *(const short8*)(qm + arow + 32 + quad * 8);
  short8 al0 = *(const short8*)(ql + arow + quad * 8);
  short8 al1 = *(const short8*)(ql + arow + 32 + quad * 8);
  long long base = (long long)bl * N * N;
#pragma unroll
  for (int ms = 0; ms < 4; ms++) {
    long long brow = qbase + (long long)(m0 + ms * 16 + lm) * CQ;
    short8 bh0 = *(const short8*)(qh + brow + quad * 8);
    short8 bh1 = *(const short8*)(qh + brow + 32 + quad * 8);
    short8 bm0 = *(const short8*)(qm + brow + quad * 8);
    short8 bm1 = *(const short8*)(qm + brow + 32 + quad * 8);
    short8 bl0 = *(const short8*)(ql + brow + quad * 8);
    short8 bl1 = *(const short8*)(ql + brow + 32 + quad * 8);
    floatx4 z = {0.f, 0.f, 0.f, 0.f};
    BF3_ACC(z, ah0, ah1, am0, am1, al0, al1, bh0, bh1, bm0, bm1, bl0, bl1);
#pragma unroll
    for (int r = 0; r < 4; r++)
      E[base + (long long)(n0 + w * 16 + quad * 4 + r) * N + (m0 + ms * 16 + lm)] =
          z[r];
  }
}

// per-row stats of E (BG batches): gmx[b0*N+row]=max, glinv=1/sum(exp(.-max))
__global__ void stats_kernel(const float* __restrict__ E, float* __restrict__ gmx,
                             float* __restrict__ glinv, int b0) {
  const int N = N_DIM;
  long long row = blockIdx.x;  // 0 .. BG*N-1 (local)
  const float* p = E + row * N;
  int t = threadIdx.x;
  float v[8];
#pragma unroll
  for (int i = 0; i < 8; i++) v[i] = p[t + i * 256];
  float m = v[0];
#pragma unroll
  for (int i = 1; i < 8; i++) m = fmaxf(m, v[i]);
  for (int o = 32; o > 0; o >>= 1) m = fmaxf(m, __shfl_down(m, o, 64));
  __shared__ float red[4];
  int wid = t >> 6, lane = t & 63;
  if (lane == 0) red[wid] = m;
  __syncthreads();
  m = fmaxf(fmaxf(red[0], red[1]), fmaxf(red[2], red[3]));
  __syncthreads();
  float s = 0.f;
#pragma unroll
  for (int i = 0; i < 8; i++) s += __expf(v[i] - m);
  for (int o = 32; o > 0; o >>= 1) s += __shfl_down(s, o, 64);
  if (lane == 0) red[wid] = s;
  __syncthreads();
  if (t == 0) {
    s = red[0] + red[1] + red[2] + red[3];
    gmx[(long long)b0 * N + row] = m;
    glinv[(long long)b0 * N + row] = 1.0f / s;
  }
}

// build 8 attT values from an E row (symmetry: attT[m][n] = exp(E[m][n]-mx[n])*linv[n])
__device__ inline void build_att_frag(const float* __restrict__ Erow,
                                      const float* __restrict__ mxp,
                                      const float* __restrict__ lip, int idx,
                                      float& cs, short8& bh, short8& bm, short8& bl) {
  float4 e0 = *(const float4*)(Erow + idx);
  float4 e1 = *(const float4*)(Erow + idx + 4);
  float4 x0 = *(const float4*)(mxp + idx);
  float4 x1 = *(const float4*)(mxp + idx + 4);
  float4 l0 = *(const float4*)(lip + idx);
  float4 l1 = *(const float4*)(lip + idx + 4);
  float e[8] = {e0.x, e0.y, e0.z, e0.w, e1.x, e1.y, e1.z, e1.w};
  float mx[8] = {x0.x, x0.y, x0.z, x0.w, x1.x, x1.y, x1.z, x1.w};
  float li[8] = {l0.x, l0.y, l0.z, l0.w, l1.x, l1.y, l1.z, l1.w};
#pragma unroll
  for (int j = 0; j < 8; j++) {
    float a = __expf(e[j] - mx[j]) * li[j];
    cs += a;
    short h, m, l;
    split_bf16x3(a, h, m, l);
    bh[j] = h;
    bm[j] = m;
    bl[j] = l;
  }
}

// D[b,c,m] = Hp[b,c,m] - (sum_n val[c][n]*attT[m][n]) / (1e-9 + cs[m])
// attT built in-register from E rows (symmetry); val from bf16x3 planes; no LDS.
// b = b0 + blockIdx.z; E indexed by local batch blockIdx.z.
// grid (N/64 m-tiles, C/64 c-tiles, BG), block 256 = 4 waves; wave w -> m-sub w*16.
__global__ __launch_bounds__(256) void pv_mfma(
    const short* __restrict__ vh, const short* __restrict__ vm,
    const short* __restrict__ vl, const float* __restrict__ E,
    const float* __restrict__ gmx, const float* __restrict__ glinv,
    const float* __restrict__ Hp, long long shB, float* __restrict__ D, int b0) {
  const int N = N_DIM;
  int bl_ = blockIdx.z;
  int b = b0 + bl_;
  int m0 = blockIdx.x * 64;
  int c0 = blockIdx.y * 64;
  int t = threadIdx.x;
  int w = t >> 6, lane = t & 63, quad = lane >> 4, lm = lane & 15;
  int mt = m0 + w * 16 + lm;  // this lane's B-row (output column)
  const float* Erow = E + (long long)bl_ * N * N + (long long)mt * N;
  const float* mxp = gmx + (long long)b * N;
  const float* lip = glinv + (long long)b * N;
  long long vbase = (long long)b * C_DIM * N;
  floatx4 pacc[4];
#pragma unroll
  for (int cb = 0; cb < 4; cb++) {
    floatx4 z = {0.f, 0.f, 0.f, 0.f};
    pacc[cb] = z;
  }
  float cs = 0.f;
  for (int n0 = 0; n0 < N; n0 += 64) {
    short8 bh0, bm0, bl0, bh1, bm1, bl1;
    build_att_frag(Erow, mxp, lip, n0 + quad * 8, cs, bh0, bm0, bl0);
    build_att_frag(Erow, mxp, lip, n0 + 32 + quad * 8, cs, bh1, bm1, bl1);
#pragma unroll
    for (int cb = 0; cb < 4; cb++) {
      long long vrow = vbase + (long long)(c0 + cb * 16 + lm) * N + n0;
      short8 Ah0 = *(const short8*)(vh + vrow + quad * 8);
      short8 Ah1 = *(const short8*)(vh + vrow + 32 + quad * 8);
      short8 Am0 = *(const short8*)(vm + vrow + quad * 8);
      short8 Am1 = *(const short8*)(vm + vrow + 32 + quad * 8);
      short8 Al0 = *(const short8*)(vl + vrow + quad * 8);
      short8 Al1 = *(const short8*)(vl + vrow + 32 + quad * 8);
      floatx4 z = pacc[cb];
      BF3_ACC(z, Ah0, Ah1, Am0, Am1, Al0, Al1, bh0, bh1, bm0, bm1, bl0, bl1);
      pacc[cb] = z;
    }
  }
  // cs: each lane summed k-slices {quad*8..+8} and {32+quad*8..+8} per 64-chunk;
  // xor over quad bits completes the column sum for this lane's mt.
  cs += __shfl_xor(cs, 16, 64);
  cs += __shfl_xor(cs, 32, 64);
  float inv = 1.0f / (1e-9f + cs);
  const float* hp = Hp + (long long)b * shB;
  float* db = D + (long long)b * C_DIM * N;
#pragma unroll
  for (int cb = 0; cb < 4; cb++) {
#pragma unroll
    for (int r = 0; r < 4; r++) {
      int c = c0 + cb * 16 + quad * 4 + r;
      db[(long long)c * N + mt] = hp[(long long)c * N + mt] - pacc[cb][r] * inv;
    }
  }
}

extern "C" void kernel_launch(void* const* d_in, const int* in_sizes, int n_in,
                              void* d_out, int out_size, void* d_ws, size_t ws_size,
                              hipStream_t stream) {
  const float* x = (const float*)d_in[0];
  const float* xyz = (const float*)d_in[1];
  const float* conv1_w = (const float*)d_in[2];
  const float* convpos_w = (const float*)d_in[3];
  const float* bn1_g = (const float*)d_in[4];
  const float* bn1_b = (const float*)d_in[5];
  const float* bn1_m = (const float*)d_in[6];
  const float* bn1_v = (const float*)d_in[7];
  const float* Wqk = (const float*)d_in[8];   // [4,64,256]
  const float* Wv = (const float*)d_in[9];    // [4,256,256]
  const float* bv = (const float*)d_in[10];   // [4,256]
  const float* Wt = (const float*)d_in[11];   // [4,256,256]
  const float* bt = (const float*)d_in[12];   // [4,256]
  const float* bng = (const float*)d_in[13];
  const float* bnb = (const float*)d_in[14];
  const float* bnm = (const float*)d_in[15];
  const float* bnv = (const float*)d_in[16];
  float* out = (float*)d_out;

  const long long BCN = (long long)B_DIM * C_DIM * N_DIM;
  const long long CN = (long long)C_DIM * N_DIM;
  const long long BN = (long long)B_DIM * N_DIM;
  // ws footprint: 16+16+16+0.125+64+6+24 = ~142.1 MiB (round-5-proven <=196 MiB)
  float* ws = (float*)d_ws;
  float* pos = ws;                                  // BCN f32      (16 MiB)
  float* h0 = pos + BCN;                            // BCN f32      (16 MiB)
  float* dbuf = h0 + BCN;                           // BCN f32      (16 MiB)
  float* gmx = dbuf + BCN;                          // BN f32
  float* glinv = gmx + BN;                          // BN f32
  float* E = glinv + BN;                            // BG*N*N f32   (64 MiB)
  short* qh = (short*)(E + (long long)BG * N_DIM * N_DIM);  // BN*64 (2 MiB)
  short* qm = qh + BN * CQ;
  short* ql = qm + BN * CQ;
  short* vh = ql + BN * CQ;                         // BCN shorts   (8 MiB)
  short* vm = vh + BCN;
  short* vl = vm + BCN;

  dim3 blk(256);

  pos_kernel<<<dim3(N_DIM / 256, C_DIM, B_DIM), blk, 0, stream>>>(convpos_w, xyz, pos);

  // h0 = relu(bn1(conv1_w @ x))
  gemm_wx<<<dim3(N_DIM / TN, C_DIM / TM, B_DIM), blk, 0, stream>>>(
      conv1_w, x, CN, nullptr, 0, nullptr,
      bn1_g, bn1_b, bn1_m, bn1_v, nullptr, 0, h0, CN,
      nullptr, nullptr, nullptr, 0, C_DIM, C_DIM);

  for (int i = 0; i < 4; i++) {
    const float* hp = (i == 0) ? h0 : out + (long long)(i - 1) * CN;
    long long shp = (i == 0) ? CN : 4 * CN;

    // q planes (transposed [n][64]) = split(Wqk_i @ (h + pos))
    gemm_wx<<<dim3(N_DIM / TN, 1, B_DIM), blk, 0, stream>>>(
        Wqk + (long long)i * CQ * C_DIM, hp, shp, pos, CN, nullptr,
        nullptr, nullptr, nullptr, nullptr, nullptr, 0,
        nullptr, 0, qh, qm, ql, 2, CQ, C_DIM);

    // val planes [c][n] = split(Wv_i @ (h + pos) + bv_i)
    gemm_wx<<<dim3(N_DIM / TN, C_DIM / TM, B_DIM), blk, 0, stream>>>(
        Wv + (long long)i * C_DIM * C_DIM, hp, shp, pos, CN, bv + i * C_DIM,
        nullptr, nullptr, nullptr, nullptr, nullptr, 0,
        nullptr, 0, vh, vm, vl, 1, C_DIM, C_DIM);

    for (int b0 = 0; b0 < B_DIM; b0 += BG) {
      energy_mfma<<<dim3(N_DIM / 64, N_DIM / 64, BG), blk, 0, stream>>>(
          qh, qm, ql, E, b0);
      stats_kernel<<<dim3(BG * N_DIM), blk, 0, stream>>>(E, gmx, glinv, b0);
      pv_mfma<<<dim3(N_DIM / 64, C_DIM / 64, BG), blk, 0, stream>>>(
          vh, vm, vl, E, gmx, glinv, hp, shp, dbuf, b0);
    }

    // out_i = h + relu(bn_i(Wt_i @ d + bt_i))
    gemm_wx<<<dim3(N_DIM / TN, C_DIM / TM, B_DIM), blk, 0, stream>>>(
        Wt + (long long)i * C_DIM * C_DIM, dbuf, CN, nullptr, 0, bt + i * C_DIM,
        bng + i * C_DIM, bnb + i * C_DIM, bnm + i * C_DIM, bnv + i * C_DIM,
        hp, shp, out + (long long)i * CN, 4 * CN,
        nullptr, nullptr, nullptr, 0, C_DIM, C_DIM);
  }
}